// Round 4
// baseline (518.057 us; speedup 1.0000x reference)
//
#include <hip/hip_runtime.h>

// B=2, T=12, C=128, H=W=32, heads=4, dh=32, layers=5. fp32 I/O.
// Algebra: key-axis softmax cancels q-conv & att_b; attention weights are
// query-independent (head output broadcast over the 12 frames).
// Layout: channels-last fp32 activations [img][1024px][128c] + padded bf16
// copies A2[img][34*34 pos][128c].
// Round 4: convs moved to 32x32x16 MFMA (half the MFMA instructions, one
// ds_read_b128 per MFMA, 16-float acc). New B layout [tap][k16][kh][co]x8j
// makes the per-tap weight prefetch two contiguous 512B segments per wave.
// Block 256thr = 4 waves (one 32-co group each), tile 32px x 128co,
// grid (32,24) = 768 blocks = 3 blocks/CU; A-slab in LDS (9x tap reuse).
#define NELEM 3145728
#define IMG 24
#define CH 128
#define HW 1024
#define PADP 1156          // 34*34
#define A2IMG 147968       // 1156*128

using short8   = __attribute__((ext_vector_type(8))) short;
using float4v  = __attribute__((ext_vector_type(4))) float;
using float16v = __attribute__((ext_vector_type(16))) float;

__device__ inline unsigned short f2bf(float f){
    union { float f; unsigned u; } c; c.f = f;
    return (unsigned short)((c.u + 0x7FFF + ((c.u >> 16) & 1)) >> 16);
}
__device__ inline float bf2f(unsigned short h){
    union { unsigned u; float f; } c; c.u = ((unsigned)h) << 16; return c.f;
}

// ---------------- fused prep: weight transforms + A2 borders + init ----------------
// Dense W3 layout: short8 idx = ((tap*8 + k16)*2 + kh)*128 + co ; elems j=ci%8,
// ci = k16*16 + kh*8 + j. KV W3: short8 idx = ((tap*2 + k16)*2 + kh)*128 + co,
// ci_local = k16*16 + kh*8 + j (head = co>>5).
__global__ __launch_bounds__(256) void k_prep(
    const float* __restrict__ ff1w, const float* __restrict__ ff2w,
    const float* __restrict__ kvw, const float* __restrict__ input,
    unsigned short* __restrict__ Wd, unsigned short* __restrict__ Wkv,
    unsigned short* __restrict__ A2a, unsigned short* __restrict__ A2v,
    float* __restrict__ cur)
{
    int gid = blockIdx.x * 256 + threadIdx.x;        // 12720*256 = 3256320 exact
    if (gid < 1474560) {
        int idx = gid;
        int li2 = idx / 147456, r1 = idx - li2 * 147456;
        int j = r1 & 7, co = (r1 >> 3) & 127;
        int kh = (r1 >> 10) & 1, k16 = (r1 >> 11) & 7, tap = r1 >> 14;
        int ci = k16 * 16 + kh * 8 + j;
        const float* base = ((li2 & 1) ? ff2w : ff1w) + (size_t)(li2 >> 1) * 147456;
        Wd[idx] = f2bf(base[(co * 128 + ci) * 9 + tap]);
    } else if (gid < 1658880) {
        int idx = gid - 1474560;
        int li = idx / 36864, r1 = idx - li * 36864;
        int j = r1 & 7, co = (r1 >> 3) & 127;
        int kh = (r1 >> 10) & 1, k16 = (r1 >> 11) & 1, tap = r1 >> 12;
        int h = co >> 5, colc = co & 31, cil = k16 * 16 + kh * 8 + j;
        Wkv[idx] = f2bf(kvw[((size_t)((li * 4 + h) * 32 + colc) * 32 + cil) * 9 + tap]);
    } else if (gid < 2469888) {
        int g2 = gid - 1658880;                      // 2*24*132*128
        int c = g2 & 127, r = g2 >> 7;
        int bp = r % 132, r2 = r / 132;
        int img = r2 % 24, buf = r2 / 24;
        int pos;
        if (bp < 34) pos = bp;
        else if (bp < 68) pos = 33 * 34 + (bp - 34);
        else if (bp < 100) pos = (bp - 68 + 1) * 34;
        else pos = (bp - 100 + 1) * 34 + 33;
        unsigned short* p = buf ? A2v : A2a;
        p[(size_t)img * A2IMG + pos * 128 + c] = 0;
    } else {
        int g2 = gid - 2469888;                      // 24*1024*32
        int c4 = (g2 & 31) * 4, px = (g2 >> 5) & 1023, img = g2 >> 15;
        float4v v;
        #pragma unroll
        for (int j = 0; j < 4; j++)
            v[j] = input[((size_t)img * 128 + c4 + j) * HW + px];
        *(float4v*)(cur + ((size_t)img * HW + px) * 128 + c4) = v;
        int pos = ((px >> 5) + 1) * 34 + (px & 31) + 1;
        unsigned short* ap = A2a + ((size_t)img * PADP + pos) * 128 + c4;
        #pragma unroll
        for (int j = 0; j < 4; j++) ap[j] = f2bf(v[j]);
    }
}

// ---------------- implicit-GEMM 3x3 conv, LDS-staged A, 32x32x16 MFMA ----------------
// grid (32 y-rows, 24 img). Block 256 = 4 waves; tile 32px x 128co.
// Wave w owns co group [w*32, w*32+32): ONE 32x32 output fragment.
// A-slab (3 padded rows x 34px x 128ch) staged once to LDS (9x tap reuse);
// px stride 136 shorts (16B-aligned b128). Per k16-step: 1 ds_read_b128 (A,
// ci slice 16B) + 1 MFMA. B: per-tap double-buffered coalesced b128 loads.
// A frag: row=lane&31 (px), k=(lane>>5)*8+j. B frag: k=(lane>>5)*8+j, col=lane&31.
// C/D: col=lane&31 (co), row=(reg&3)+8*(reg>>2)+4*(lane>>5) (px).
template<bool GROUPED, bool RELU, bool RES, bool EF32, bool EA2, bool STAT>
__global__ __launch_bounds__(256, 3) void k_conv(
    const unsigned short* __restrict__ a2in, const unsigned short* __restrict__ w2,
    const float* __restrict__ bias, const float* __restrict__ res,
    float* __restrict__ outf, unsigned short* __restrict__ outa2,
    float* __restrict__ pstat)
{
    const int y = blockIdx.x;                   // output row 0..31
    const int img = blockIdx.y;
    const int t = threadIdx.x;
    const int wave = t >> 6, lane = t & 63;
    const int col = lane & 31, kh = lane >> 5;
    const int cog = wave * 32;                  // wave's co base
    const int head = wave;                      // grouped head / GN group

    constexpr int NK16 = GROUPED ? 2 : 8;       // k16 steps per tap

    __shared__ unsigned short sA[102 * 136];    // 27744 B

    // stage: padded rows y..y+2 (contiguous slab), 102px x 16 groups of 8ch
    const unsigned short* slab = a2in + (size_t)img * A2IMG + (size_t)y * 34 * 128;
    #pragma unroll
    for (int it = 0; it < 7; it++) {
        int u = it * 256 + t;
        if (u < 1632) {
            int px = u >> 4, g = u & 15;
            short8 vv = *reinterpret_cast<const short8*>(slab + px * 128 + g * 8);
            *reinterpret_cast<short8*>(sA + px * 136 + g * 8) = vv;
        }
    }

    const short8* w8 = reinterpret_cast<const short8*>(w2);
    const int bl = kh * 128 + cog + col;        // per-lane short8 index into W3

    short8 bfr[2][NK16];                        // [tap parity][k16]
    auto loadB = [&](int tap, int buf){
        #pragma unroll
        for (int k16 = 0; k16 < NK16; k16++)
            bfr[buf][k16] = w8[(tap * NK16 + k16) * 256 + bl];
    };
    loadB(0, 0);

    float16v acc;
    #pragma unroll
    for (int r = 0; r < 16; r++) acc[r] = 0.f;

    __syncthreads();

    const int cibase = (GROUPED ? head * 32 : 0) + kh * 8;
    #pragma unroll
    for (int tap = 0; tap < 9; tap++) {
        if (tap + 1 < 9) loadB(tap + 1, (tap + 1) & 1);
        const int ky = tap / 3, kx = tap - ky * 3;
        const int pxl = ky * 34 + kx + col;
        #pragma unroll
        for (int k16 = 0; k16 < NK16; k16++) {
            short8 a = *reinterpret_cast<const short8*>(
                sA + pxl * 136 + cibase + k16 * 16);
            acc = __builtin_amdgcn_mfma_f32_32x32x16_bf16(
                a, bfr[tap & 1][k16], acc, 0, 0, 0);
        }
    }

    // epilogue: co = cog+col, px = (r&3) + 8*(r>>2) + 4*kh
    float s1 = 0.f, s2 = 0.f;
    const int co = cog + col;
    const float bb = bias[co];
    #pragma unroll
    for (int r = 0; r < 16; r++) {
        int pxr = (r & 3) + 8 * (r >> 2) + 4 * kh;
        int px = y * 32 + pxr;
        float val = acc[r] + bb;
        if (RELU) val = fmaxf(val, 0.f);
        size_t ci = ((size_t)img * HW + px) * 128 + co;
        if (RES) val += res[ci];
        if (EF32) outf[ci] = val;
        if (EA2) {
            int pos = (y + 1) * 34 + pxr + 1;
            outa2[((size_t)img * PADP + pos) * 128 + co] = f2bf(val);
        }
        if (STAT) { s1 += val; s2 += val * val; }
    }
    if (STAT) {
        #pragma unroll
        for (int o = 32; o > 0; o >>= 1) {
            s1 += __shfl_down(s1, o); s2 += __shfl_down(s2, o);
        }
        if (lane == 0) {
            atomicAdd(&pstat[(img * 4 + head) * 2], s1);
            atomicAdd(&pstat[(img * 4 + head) * 2 + 1], s2);
        }
    }
}

// ---------------- attention logit conv (reads padded bf16 A2v) ----------------
__global__ __launch_bounds__(256) void k_attn(
    const unsigned short* __restrict__ a2v, const float* __restrict__ aw,
    float* __restrict__ ak, float* __restrict__ pstat)
{
    const int img = blockIdx.x;            // b*12 + l
    const int h = blockIdx.y;
    const int y0 = blockIdx.z * 8;
    const int t = threadIdx.x;
    const int b = img / 12, l = img - b * 12;

    if (blockIdx.x == 0 && blockIdx.y == 0 && blockIdx.z == 0 && t < 192)
        pstat[t] = 0.f;                     // zero GN stats for this layer's ff2

    __shared__ float sxv[32 * 341];         // ci-major, pos stride 341
    __shared__ float spos[32];
    if (t < 32) {
        int j2 = t & ~1;
        float freq = __expf(-(float)j2 * 0.28782313662425576f);
        float ang = (float)l * freq;
        spos[t] = (t & 1) ? __cosf(ang) : __sinf(ang);
    }
    __syncthreads();

    // stage 10 padded rows x 34 cols x 32 ci, add pos on interior
    const unsigned short* vb = a2v + (size_t)img * A2IMG + h * 32;
    for (int idx = t; idx < 1360; idx += 256) {
        int q = idx & 3, pos = idx >> 2;
        int ppos = y0 * 34 + pos;
        int row = y0 + pos / 34, col = pos - (pos / 34) * 34;
        bool inter = (row >= 1 && row <= 32 && col >= 1 && col <= 32);
        short8 vv = *reinterpret_cast<const short8*>(vb + (size_t)ppos * 128 + q * 8);
        #pragma unroll
        for (int j = 0; j < 8; j++) {
            float f = bf2f((unsigned short)vv[j]);
            if (inter) f += spos[q * 8 + j];
            sxv[(q * 8 + j) * 341 + pos] = f;
        }
    }
    __syncthreads();

    const float* wb = aw + (h * 64 + 32) * 9;   // K-half weights (uniform -> s_load)
    const int r = t >> 5, xx = t & 31;
    float acc = 0.f;
    #pragma unroll 4
    for (int ci = 0; ci < 32; ci++) {
        #pragma unroll
        for (int ky = 0; ky < 3; ky++)
            #pragma unroll
            for (int kx = 0; kx < 3; kx++)
                acc = fmaf(sxv[ci * 341 + (r + ky) * 34 + xx + kx],
                           wb[ci * 9 + ky * 3 + kx], acc);
    }
    ak[((b * 4 + h) * 12 + l) * HW + (y0 + r) * 32 + xx] = acc;
}

// ---------------- fused softmax + weighted sum + residual (+A2a emit) ----------------
__global__ __launch_bounds__(256) void k_wsum(const float* __restrict__ ak,
    const float* __restrict__ v, float* __restrict__ cur,
    unsigned short* __restrict__ a2a)
{
    int gid = blockIdx.x * 256 + threadIdx.x;   // 2*1024*32
    int c4 = (gid & 31) * 4, px = (gid >> 5) & 1023, b = gid >> 15;
    int h = c4 >> 5;
    const float* wp = ak + ((b * 4 + h) * 12) * HW + px;
    float a[12], m = -1e30f;
    #pragma unroll
    for (int l = 0; l < 12; l++) { a[l] = wp[l * HW]; m = fmaxf(m, a[l]); }
    float ssum = 0.f;
    #pragma unroll
    for (int l = 0; l < 12; l++) { a[l] = __expf(a[l] - m); ssum += a[l]; }
    float invs = 1.f / ssum;
    float4v s = (float4v){0.f,0.f,0.f,0.f};
    #pragma unroll
    for (int l = 0; l < 12; l++) {
        float4v vv = *(const float4v*)(v + (((size_t)(b * 12 + l) * HW) + px) * 128 + c4);
        #pragma unroll
        for (int j = 0; j < 4; j++) s[j] += a[l] * vv[j];
    }
    #pragma unroll
    for (int j = 0; j < 4; j++) s[j] *= invs;
    int pos = ((px >> 5) + 1) * 34 + (px & 31) + 1;
    #pragma unroll
    for (int l = 0; l < 12; l++) {
        size_t ci = (((size_t)(b * 12 + l) * HW) + px) * 128 + c4;
        float4v cv = *(float4v*)(cur + ci);
        #pragma unroll
        for (int j = 0; j < 4; j++) cv[j] += s[j];
        *(float4v*)(cur + ci) = cv;
        unsigned short* ap = a2a + ((size_t)(b * 12 + l) * PADP + pos) * 128 + c4;
        #pragma unroll
        for (int j = 0; j < 4; j++) ap[j] = f2bf(cv[j]);
    }
}

// ---------------- GroupNorm finalize+apply (in-place on cur / final NCHW) ----------------
template<bool LAST>
__global__ __launch_bounds__(256) void k_gnapply(const float* __restrict__ y,
    const float* __restrict__ pstat, const float* __restrict__ gw,
    const float* __restrict__ gb, float* __restrict__ cur,
    unsigned short* __restrict__ a2a, float* __restrict__ outp)
{
    int gid = blockIdx.x * 256 + threadIdx.x;   // 24*1024*32
    if (!LAST) {
        int c4 = (gid & 31) * 4, px = (gid >> 5) & 1023, img = gid >> 15;
        int g = c4 >> 5;
        float S = pstat[(img * 4 + g) * 2], Q = pstat[(img * 4 + g) * 2 + 1];
        float mu = S * (1.f / 32768.f);
        float inv = rsqrtf(Q * (1.f / 32768.f) - mu * mu + 1e-5f);
        float4v vv = *(const float4v*)(y + ((size_t)img * HW + px) * 128 + c4);
        int pos = ((px >> 5) + 1) * 34 + (px & 31) + 1;
        size_t ci = ((size_t)img * HW + px) * 128 + c4;
        unsigned short* ap = a2a + ((size_t)img * PADP + pos) * 128 + c4;
        #pragma unroll
        for (int j = 0; j < 4; j++) {
            float val = (vv[j] - mu) * inv * gw[c4 + j] + gb[c4 + j];
            vv[j] = val;
            ap[j] = f2bf(val);
        }
        *(float4v*)(cur + ci) = vv;
    } else {
        int px4 = (gid & 255) * 4, c = (gid >> 8) & 127, img = gid >> 15;
        int g = c >> 5;
        float S = pstat[(img * 4 + g) * 2], Q = pstat[(img * 4 + g) * 2 + 1];
        float mu = S * (1.f / 32768.f);
        float inv = rsqrtf(Q * (1.f / 32768.f) - mu * mu + 1e-5f);
        float gg = gw[c], bb = gb[c];
        float4v o;
        #pragma unroll
        for (int j = 0; j < 4; j++) {
            float val = y[((size_t)img * HW + px4 + j) * 128 + c];
            o[j] = (val - mu) * inv * gg + bb;
        }
        *(float4v*)(outp + ((size_t)img * 128 + c) * HW + px4) = o;
    }
}

extern "C" void kernel_launch(void* const* d_in, const int* in_sizes, int n_in,
                              void* d_out, int out_size, void* d_ws, size_t ws_size,
                              hipStream_t stream)
{
    const float* input = (const float*)d_in[0];
    // d_in[1] q_w, d_in[2] q_b, d_in[6] att_b cancel in key-axis softmax.
    const float* kv_w  = (const float*)d_in[3];
    const float* kv_b  = (const float*)d_in[4];
    const float* att_w = (const float*)d_in[5];
    const float* ff1_w = (const float*)d_in[7];
    const float* ff1_b = (const float*)d_in[8];
    const float* ff2_w = (const float*)d_in[9];
    const float* ff2_b = (const float*)d_in[10];
    const float* gn_w  = (const float*)d_in[11];
    const float* gn_b  = (const float*)d_in[12];

    // ws layout (~30.5 MB): no buffer aliases another live buffer.
    float* ws  = (float*)d_ws;
    float* cur = ws;                          // CL fp32 (24,1024,128)
    float* ak  = ws + (size_t)NELEM;          // 98304
    float* pstat = ak + 98304;                // 192
    unsigned short* W2d  = (unsigned short*)(pstat + 192);   // 1,474,560
    unsigned short* W2kv = W2d + 1474560;                    // 184,320
    unsigned short* A2v  = W2kv + 184320;                    // 24*147968
    unsigned short* A2a  = A2v + (size_t)IMG * A2IMG;        // 24*147968
    // d_out doubles as the fp32 v buffer (dead before the final output write).
    float* v    = (float*)d_out;
    float* outp = (float*)d_out;

    k_prep<<<12720, 256, 0, stream>>>(ff1_w, ff2_w, kv_w, input,
                                      W2d, W2kv, A2a, A2v, cur);

    for (int li = 0; li < 5; li++) {
        // v (d_out) = grouped conv(A2a) + kv_b ; also emit A2v bf16
        k_conv<true, false, false, true, true, false><<<dim3(32, IMG), 256, 0, stream>>>(
            A2a, W2kv + (size_t)li * 36864, kv_b + li * 128, nullptr, v, A2v, nullptr);
        // attention logits from k = v + pos (also zeroes pstat for this layer)
        k_attn<<<dim3(IMG, 4, 4), 256, 0, stream>>>(A2v, att_w + (size_t)li * 2304, ak, pstat);
        // cur += softmax-weighted sum of v (broadcast over frames); emit A2a
        k_wsum<<<256, 256, 0, stream>>>(ak, v, cur, A2a);
        // f1 = relu(conv(A2a, ff1)) -> A2v only
        k_conv<false, true, false, false, true, false><<<dim3(32, IMG), 256, 0, stream>>>(
            A2a, W2d + (size_t)(li * 2 + 0) * 147456, ff1_b + li * 128, nullptr, nullptr, A2v, nullptr);
        // cur = conv(A2v, ff2) + cur  (in-place, element-wise) + GN partial stats
        k_conv<false, false, true, true, false, true><<<dim3(32, IMG), 256, 0, stream>>>(
            A2v, W2d + (size_t)(li * 2 + 1) * 147456, ff2_b + li * 128, cur, cur, nullptr, pstat);
        // GN apply: in-place on cur + A2a emit, or final NCHW transpose to d_out
        if (li == 4)
            k_gnapply<true><<<3072, 256, 0, stream>>>(cur, pstat, gn_w + li * 128,
                gn_b + li * 128, nullptr, nullptr, outp);
        else
            k_gnapply<false><<<3072, 256, 0, stream>>>(cur, pstat, gn_w + li * 128,
                gn_b + li * 128, cur, A2a, nullptr);
    }
}

// Round 5
// 507.438 us; speedup vs baseline: 1.0209x; 1.0209x over previous
//
#include <hip/hip_runtime.h>

// B=2, T=12, C=128, H=W=32, heads=4, dh=32, layers=5. fp32 I/O.
// Algebra: key-axis softmax cancels q-conv & att_b; attention weights are
// query-independent (head output broadcast over the 12 frames).
// Round 5: dispatch-count attack (31 -> 22) + traffic cuts.
//  - k_kvattn fuses grouped kv-conv + attn-logit conv per (img, head, 8-row
//    strip); v halo rows recomputed; k=v+pos written straight to LDS (lane=ci
//    so pos-add is a register scalar). A2v copy of v eliminated.
//  - GroupNorm-apply dispatches eliminated: cur stays pre-GN (=F); consumers
//    (kv-stage, wsum) apply GN on the fly from ping-ponged pstat sets.
//  - ff1 stages from fp32 cur (border-checked) -> wsum's A2a emit removed.
//  - A2v remains only as the ff1->ff2 padded bf16 buffer.
#define NELEM 3145728
#define IMG 24
#define CH 128
#define HW 1024
#define PADP 1156          // 34*34
#define A2IMG 147968       // 1156*128

using short8   = __attribute__((ext_vector_type(8))) short;
using ushort4v = __attribute__((ext_vector_type(4))) unsigned short;
using float4v  = __attribute__((ext_vector_type(4))) float;
using float16v = __attribute__((ext_vector_type(16))) float;

__device__ inline unsigned short f2bf(float f){
    union { float f; unsigned u; } c; c.f = f;
    return (unsigned short)((c.u + 0x7FFF + ((c.u >> 16) & 1)) >> 16);
}

// ---------------- fused prep: weight transforms + A2v borders + init ----------------
// Dense W3 layout: short8 idx = ((tap*8 + k16)*2 + kh)*128 + co ; j=ci%8,
// ci = k16*16 + kh*8 + j. KV W3: short8 idx = ((tap*2 + k16)*2 + kh)*128 + co,
// ci_local = k16*16 + kh*8 + j (head = co>>5).
__global__ __launch_bounds__(256) void k_prep(
    const float* __restrict__ ff1w, const float* __restrict__ ff2w,
    const float* __restrict__ kvw, const float* __restrict__ input,
    unsigned short* __restrict__ Wd, unsigned short* __restrict__ Wkv,
    unsigned short* __restrict__ A2v, float* __restrict__ cur)
{
    int gid = blockIdx.x * 256 + threadIdx.x;        // 11136*256 = 2850816 exact
    if (gid < 1474560) {
        int idx = gid;
        int li2 = idx / 147456, r1 = idx - li2 * 147456;
        int j = r1 & 7, co = (r1 >> 3) & 127;
        int kh = (r1 >> 10) & 1, k16 = (r1 >> 11) & 7, tap = r1 >> 14;
        int ci = k16 * 16 + kh * 8 + j;
        const float* base = ((li2 & 1) ? ff2w : ff1w) + (size_t)(li2 >> 1) * 147456;
        Wd[idx] = f2bf(base[(co * 128 + ci) * 9 + tap]);
    } else if (gid < 1658880) {
        int idx = gid - 1474560;
        int li = idx / 36864, r1 = idx - li * 36864;
        int j = r1 & 7, co = (r1 >> 3) & 127;
        int kh = (r1 >> 10) & 1, k16 = (r1 >> 11) & 1, tap = r1 >> 12;
        int h = co >> 5, colc = co & 31, cil = k16 * 16 + kh * 8 + j;
        Wkv[idx] = f2bf(kvw[((size_t)((li * 4 + h) * 32 + colc) * 32 + cil) * 9 + tap]);
    } else if (gid < 2064384) {
        int g2 = gid - 1658880;                      // 24*132*128 = 405504
        int c = g2 & 127, r = g2 >> 7;
        int bp = r % 132, img = r / 132;
        int pos;
        if (bp < 34) pos = bp;
        else if (bp < 68) pos = 33 * 34 + (bp - 34);
        else if (bp < 100) pos = (bp - 68 + 1) * 34;
        else pos = (bp - 100 + 1) * 34 + 33;
        A2v[(size_t)img * A2IMG + pos * 128 + c] = 0;
    } else {
        int g2 = gid - 2064384;                      // 24*1024*32
        int c4 = (g2 & 31) * 4, px = (g2 >> 5) & 1023, img = g2 >> 15;
        float4v v;
        #pragma unroll
        for (int j = 0; j < 4; j++)
            v[j] = input[((size_t)img * 128 + c4 + j) * HW + px];
        *(float4v*)(cur + ((size_t)img * HW + px) * 128 + c4) = v;
    }
}

// ---------------- fused kv-conv + attention-logit conv ----------------
// grid (24 img, 4 h, 4 strips). Block 256 = 4 waves.
// Stage GN(cur) rows y0-2..y0+9 x cols -1..32 x head's 32ch as bf16 in LDS
// (px stride 40 shorts: 16B-aligned b128, conflict-free). Grouped conv via
// 32x32x16 MFMA, one row-fragment per f (10 rows incl. halo; rows y0..y0+7
// written to global v). k = v + pos goes straight into sxv[ci][pos] f32
// (lane=ci so pos is a register scalar; writes conflict-free, stride 341).
// Then the 3x3x32ci logit conv (one output px per thread) -> ak.
// Also zeroes this layer's pstat set (block 0) before ff2's atomics.
__global__ __launch_bounds__(256, 2) void k_kvattn(
    const float* __restrict__ cur, const unsigned short* __restrict__ wkv,
    const float* __restrict__ kvb, const float* __restrict__ aw,
    const float* __restrict__ pstatp, const float* __restrict__ gw,
    const float* __restrict__ gb, float* __restrict__ v,
    float* __restrict__ ak, float* __restrict__ pstatz)
{
    const int img = blockIdx.x, h = blockIdx.y, y0 = blockIdx.z * 8;
    const int t = threadIdx.x;
    const int b = img / 12, l = img - b * 12;

    if (blockIdx.x == 0 && blockIdx.y == 0 && blockIdx.z == 0 && t < 192)
        pstatz[t] = 0.f;

    __shared__ float sxv[32 * 341];              // 43648 B
    __shared__ unsigned short slab[408 * 40];    // 32640 B (12 rows x 34 cols)
    __shared__ float spos[32], sbias[32], sgw[32], sgb[32];

    if (t < 32) {
        int j2 = t & ~1;
        float freq = __expf(-(float)j2 * 0.28782313662425576f);
        float ang = (float)l * freq;
        spos[t] = (t & 1) ? __cosf(ang) : __sinf(ang);
        sbias[t] = kvb[h * 32 + t];
        sgw[t] = gw ? gw[h * 32 + t] : 1.f;
        sgb[t] = gb ? gb[h * 32 + t] : 0.f;
    }
    float mu = 0.f, inv = 1.f;
    if (pstatp) {
        float S = pstatp[(img * 4 + h) * 2], Q = pstatp[(img * 4 + h) * 2 + 1];
        mu = S * (1.f / 32768.f);
        inv = rsqrtf(Q * (1.f / 32768.f) - mu * mu + 1e-5f);
    }
    __syncthreads();

    // stage: 12 rows x 34 cols x 8 float4-groups of the head's 32 ch
    for (int u = t; u < 3264; u += 256) {
        int q = u & 7, p = u >> 3;
        int lr = p / 34, lc = p - lr * 34;
        int yr = y0 - 2 + lr, x = lc - 1;
        float4v val = (float4v){0.f, 0.f, 0.f, 0.f};
        if (yr >= 0 && yr < 32 && x >= 0 && x < 32) {
            val = *(const float4v*)(cur + ((size_t)img * HW + yr * 32 + x) * 128 + h * 32 + q * 4);
            #pragma unroll
            for (int j = 0; j < 4; j++)
                val[j] = (val[j] - mu) * inv * sgw[q * 4 + j] + sgb[q * 4 + j];
        }
        ushort4v o;
        #pragma unroll
        for (int j = 0; j < 4; j++) o[j] = f2bf(val[j]);
        *(ushort4v*)(slab + p * 40 + q * 4) = o;
    }
    __syncthreads();

    const int lane = t & 63, wave = t >> 6;
    const int colx = lane & 31, kh = lane >> 5;
    const short8* w8 = reinterpret_cast<const short8*>(wkv);

    for (int f = wave; f < 10; f += 4) {
        float16v acc;
        #pragma unroll
        for (int r = 0; r < 16; r++) acc[r] = 0.f;
        #pragma unroll
        for (int tap = 0; tap < 9; tap++) {
            const int ky = tap / 3, kx = tap - ky * 3;
            #pragma unroll
            for (int k16 = 0; k16 < 2; k16++) {
                short8 a = *reinterpret_cast<const short8*>(
                    slab + ((f + ky) * 34 + colx + kx) * 40 + k16 * 16 + kh * 8);
                short8 bf = w8[((tap * 2 + k16) * 2 + kh) * 128 + h * 32 + colx];
                acc = __builtin_amdgcn_mfma_f32_32x32x16_bf16(a, bf, acc, 0, 0, 0);
            }
        }
        const int yr = y0 - 1 + f;
        const bool rowin = (yr >= 0 && yr < 32);
        const bool vown = rowin && f >= 1 && f <= 8;   // rows this block owns
        const float posci = spos[colx], bb = sbias[colx];
        float* vrow = v + ((size_t)img * HW + yr * 32) * 128 + h * 32 + colx;
        #pragma unroll
        for (int r = 0; r < 16; r++) {
            int x2 = (r & 3) + 8 * (r >> 2) + 4 * kh;
            float val = rowin ? acc[r] + bb : 0.f;
            if (vown) vrow[(size_t)x2 * 128] = val;
            sxv[colx * 341 + f * 34 + x2 + 1] = rowin ? val + posci : 0.f;
        }
    }
    // zero padded border cols (0 and 33) of all 10 rows
    for (int u = t; u < 640; u += 256) {
        int ci = u & 31, r2 = u >> 5;
        sxv[ci * 341 + (r2 >> 1) * 34 + ((r2 & 1) ? 33 : 0)] = 0.f;
    }
    __syncthreads();

    const float* wb = aw + (h * 64 + 32) * 9;   // K-half weights (uniform)
    const int r = t >> 5, xx = t & 31;
    float acc2 = 0.f;
    #pragma unroll 4
    for (int ci = 0; ci < 32; ci++) {
        #pragma unroll
        for (int ky = 0; ky < 3; ky++)
            #pragma unroll
            for (int kx = 0; kx < 3; kx++)
                acc2 = fmaf(sxv[ci * 341 + (r + ky) * 34 + xx + kx],
                            wb[ci * 9 + ky * 3 + kx], acc2);
    }
    ak[((size_t)(b * 4 + h) * 12 + l) * HW + (y0 + r) * 32 + xx] = acc2;
}

// ---------------- implicit-GEMM 3x3 dense conv, LDS-staged A, 32x32x16 MFMA ----------------
// grid (32 y-rows, 24 img). Block 256 = 4 waves; tile 32px x 128co.
// SRC32: stage from fp32 cur (border-checked, bf16-convert). else: from padded
// bf16 A2 buffer. Wave w owns co group [w*32,w*32+32): one 32x32 fragment.
template<bool SRC32, bool RELU, bool RES, bool EF32, bool EA2, bool STAT>
__global__ __launch_bounds__(256, 3) void k_conv(
    const unsigned short* __restrict__ a2in, const float* __restrict__ src32,
    const unsigned short* __restrict__ w2, const float* __restrict__ bias,
    const float* __restrict__ res, float* __restrict__ outf,
    unsigned short* __restrict__ outa2, float* __restrict__ pstat)
{
    const int y = blockIdx.x;                   // output row 0..31
    const int img = blockIdx.y;
    const int t = threadIdx.x;
    const int wave = t >> 6, lane = t & 63;
    const int colx = lane & 31, kh = lane >> 5;
    const int cog = wave * 32;                  // wave's co base
    const int head = wave;                      // GN group

    __shared__ unsigned short sA[102 * 136];    // 27744 B

    if (SRC32) {
        // 3 rows (y-1..y+1) x 34 cols x 32 float4-groups from fp32 cur
        for (int u = t; u < 3264; u += 256) {
            int q = u & 31, p = u >> 5;
            int lr = p / 34, lc = p - lr * 34;
            int yr = y - 1 + lr, x = lc - 1;
            float4v val = (float4v){0.f, 0.f, 0.f, 0.f};
            if (yr >= 0 && yr < 32 && x >= 0 && x < 32)
                val = *(const float4v*)(src32 + ((size_t)img * HW + yr * 32 + x) * 128 + q * 4);
            ushort4v o;
            #pragma unroll
            for (int j = 0; j < 4; j++) o[j] = f2bf(val[j]);
            *(ushort4v*)(sA + p * 136 + q * 4) = o;
        }
    } else {
        const unsigned short* slab = a2in + (size_t)img * A2IMG + (size_t)y * 34 * 128;
        #pragma unroll
        for (int it = 0; it < 7; it++) {
            int u = it * 256 + t;
            if (u < 1632) {
                int px = u >> 4, g = u & 15;
                short8 vv = *reinterpret_cast<const short8*>(slab + px * 128 + g * 8);
                *reinterpret_cast<short8*>(sA + px * 136 + g * 8) = vv;
            }
        }
    }

    const short8* w8 = reinterpret_cast<const short8*>(w2);
    const int bl = kh * 128 + cog + colx;       // per-lane short8 index into W3

    short8 bfr[2][8];                           // [tap parity][k16]
    auto loadB = [&](int tap, int buf){
        #pragma unroll
        for (int k16 = 0; k16 < 8; k16++)
            bfr[buf][k16] = w8[(tap * 8 + k16) * 256 + bl];
    };
    loadB(0, 0);

    float16v acc;
    #pragma unroll
    for (int r = 0; r < 16; r++) acc[r] = 0.f;

    __syncthreads();

    const int cibase = kh * 8;
    #pragma unroll
    for (int tap = 0; tap < 9; tap++) {
        if (tap + 1 < 9) loadB(tap + 1, (tap + 1) & 1);
        const int ky = tap / 3, kx = tap - ky * 3;
        const int pxl = ky * 34 + kx + colx;
        #pragma unroll
        for (int k16 = 0; k16 < 8; k16++) {
            short8 a = *reinterpret_cast<const short8*>(
                sA + pxl * 136 + cibase + k16 * 16);
            acc = __builtin_amdgcn_mfma_f32_32x32x16_bf16(
                a, bfr[tap & 1][k16], acc, 0, 0, 0);
        }
    }

    // epilogue: co = cog+colx, px = (r&3) + 8*(r>>2) + 4*kh
    float s1 = 0.f, s2 = 0.f;
    const int co = cog + colx;
    const float bb = bias[co];
    #pragma unroll
    for (int r = 0; r < 16; r++) {
        int pxr = (r & 3) + 8 * (r >> 2) + 4 * kh;
        int px = y * 32 + pxr;
        float val = acc[r] + bb;
        if (RELU) val = fmaxf(val, 0.f);
        size_t ci = ((size_t)img * HW + px) * 128 + co;
        if (RES) val += res[ci];
        if (EF32) outf[ci] = val;
        if (EA2) {
            int pos = (y + 1) * 34 + pxr + 1;
            outa2[((size_t)img * PADP + pos) * 128 + co] = f2bf(val);
        }
        if (STAT) { s1 += val; s2 += val * val; }
    }
    if (STAT) {
        #pragma unroll
        for (int o = 32; o > 0; o >>= 1) {
            s1 += __shfl_down(s1, o); s2 += __shfl_down(s2, o);
        }
        if (lane == 0) {
            atomicAdd(&pstat[(img * 4 + head) * 2], s1);
            atomicAdd(&pstat[(img * 4 + head) * 2 + 1], s2);
        }
    }
}

// ---------------- fused softmax + weighted sum + GN-on-read residual ----------------
__global__ __launch_bounds__(256) void k_wsum(const float* __restrict__ ak,
    const float* __restrict__ v, float* __restrict__ cur,
    const float* __restrict__ pstatp, const float* __restrict__ gw,
    const float* __restrict__ gb)
{
    int gid = blockIdx.x * 256 + threadIdx.x;   // 2*1024*32
    int c4 = (gid & 31) * 4, px = (gid >> 5) & 1023, b = gid >> 15;
    int h = c4 >> 5;
    const float* wp = ak + ((b * 4 + h) * 12) * HW + px;
    float a[12], m = -1e30f;
    #pragma unroll
    for (int l = 0; l < 12; l++) { a[l] = wp[l * HW]; m = fmaxf(m, a[l]); }
    float ssum = 0.f;
    #pragma unroll
    for (int l = 0; l < 12; l++) { a[l] = __expf(a[l] - m); ssum += a[l]; }
    float invs = 1.f / ssum;
    float4v s = (float4v){0.f, 0.f, 0.f, 0.f};
    #pragma unroll
    for (int l = 0; l < 12; l++) {
        float4v vv = *(const float4v*)(v + (((size_t)(b * 12 + l) * HW) + px) * 128 + c4);
        #pragma unroll
        for (int j = 0; j < 4; j++) s[j] += a[l] * vv[j];
    }
    #pragma unroll
    for (int j = 0; j < 4; j++) s[j] *= invs;
    float gwv[4], gbv[4];
    #pragma unroll
    for (int j = 0; j < 4; j++) {
        gwv[j] = gw ? gw[c4 + j] : 1.f;
        gbv[j] = gb ? gb[c4 + j] : 0.f;
    }
    #pragma unroll
    for (int l = 0; l < 12; l++) {
        int img = b * 12 + l;
        float mu = 0.f, inv = 1.f;
        if (pstatp) {
            float S = pstatp[(img * 4 + h) * 2], Q = pstatp[(img * 4 + h) * 2 + 1];
            mu = S * (1.f / 32768.f);
            inv = rsqrtf(Q * (1.f / 32768.f) - mu * mu + 1e-5f);
        }
        size_t ci = (((size_t)img * HW) + px) * 128 + c4;
        float4v cv = *(float4v*)(cur + ci);
        #pragma unroll
        for (int j = 0; j < 4; j++)
            cv[j] = (cv[j] - mu) * inv * gwv[j] + gbv[j] + s[j];
        *(float4v*)(cur + ci) = cv;
    }
}

// ---------------- final GroupNorm + NCHW transpose ----------------
__global__ __launch_bounds__(256) void k_gnlast(const float* __restrict__ y,
    const float* __restrict__ pstat, const float* __restrict__ gw,
    const float* __restrict__ gb, float* __restrict__ outp)
{
    int gid = blockIdx.x * 256 + threadIdx.x;   // 24*1024*32
    int px4 = (gid & 255) * 4, c = (gid >> 8) & 127, img = gid >> 15;
    int g = c >> 5;
    float S = pstat[(img * 4 + g) * 2], Q = pstat[(img * 4 + g) * 2 + 1];
    float mu = S * (1.f / 32768.f);
    float inv = rsqrtf(Q * (1.f / 32768.f) - mu * mu + 1e-5f);
    float gg = gw[c], bb = gb[c];
    float4v o;
    #pragma unroll
    for (int j = 0; j < 4; j++) {
        float val = y[((size_t)img * HW + px4 + j) * 128 + c];
        o[j] = (val - mu) * inv * gg + bb;
    }
    *(float4v*)(outp + ((size_t)img * 128 + c) * HW + px4) = o;
}

extern "C" void kernel_launch(void* const* d_in, const int* in_sizes, int n_in,
                              void* d_out, int out_size, void* d_ws, size_t ws_size,
                              hipStream_t stream)
{
    const float* input = (const float*)d_in[0];
    // d_in[1] q_w, d_in[2] q_b, d_in[6] att_b cancel in key-axis softmax.
    const float* kv_w  = (const float*)d_in[3];
    const float* kv_b  = (const float*)d_in[4];
    const float* att_w = (const float*)d_in[5];
    const float* ff1_w = (const float*)d_in[7];
    const float* ff1_b = (const float*)d_in[8];
    const float* ff2_w = (const float*)d_in[9];
    const float* ff2_b = (const float*)d_in[10];
    const float* gn_w  = (const float*)d_in[11];
    const float* gn_b  = (const float*)d_in[12];

    // ws layout (~23.5 MB): no buffer aliases another live buffer.
    float* ws  = (float*)d_ws;
    float* cur = ws;                          // CL fp32 (24,1024,128)
    float* ak  = ws + (size_t)NELEM;          // 98304
    float* pstat = ak + 98304;                // 2 sets x 192 (ping-pong)
    unsigned short* W2d  = (unsigned short*)(pstat + 384);   // 1,474,560
    unsigned short* W2kv = W2d + 1474560;                    // 184,320
    unsigned short* A2v  = W2kv + 184320;                    // 24*147968
    // d_out doubles as the fp32 v buffer (dead before the final output write).
    float* v    = (float*)d_out;
    float* outp = (float*)d_out;

    k_prep<<<11136, 256, 0, stream>>>(ff1_w, ff2_w, kv_w, input, W2d, W2kv, A2v, cur);

    for (int li = 0; li < 5; li++) {
        float* psC = pstat + (li & 1) * 192;                 // this layer's stats
        const float* psP = li ? pstat + ((li - 1) & 1) * 192 : nullptr;
        const float* gwP = li ? gn_w + (li - 1) * 128 : nullptr;
        const float* gbP = li ? gn_b + (li - 1) * 128 : nullptr;

        // v = grouped conv(GN(cur)) + kv_b ; k = v + pos ; ak = logit conv(k)
        k_kvattn<<<dim3(IMG, 4, 4), 256, 0, stream>>>(
            cur, W2kv + (size_t)li * 36864, kv_b + li * 128, att_w + (size_t)li * 2304,
            psP, gwP, gbP, v, ak, psC);
        // cur = GN(cur) + softmax-weighted sum of v  (= A)
        k_wsum<<<256, 256, 0, stream>>>(ak, v, cur, psP, gwP, gbP);
        // A2v = relu(conv(cur, ff1))  (bf16 padded)
        k_conv<true, true, false, false, true, false><<<dim3(32, IMG), 256, 0, stream>>>(
            nullptr, cur, W2d + (size_t)(li * 2 + 0) * 147456, ff1_b + li * 128,
            nullptr, nullptr, A2v, nullptr);
        // cur = conv(A2v, ff2) + cur  (= F) + GN partial stats
        k_conv<false, false, true, true, false, true><<<dim3(32, IMG), 256, 0, stream>>>(
            A2v, nullptr, W2d + (size_t)(li * 2 + 1) * 147456, ff2_b + li * 128,
            cur, cur, nullptr, psC);
    }
    // final: out = GN(cur) transposed to NCHW
    k_gnlast<<<3072, 256, 0, stream>>>(cur, pstat + 0, gn_w + 4 * 128,
                                       gn_b + 4 * 128, outp);
}